// Round 10
// baseline (504.984 us; speedup 1.0000x reference)
//
#include <hip/hip_runtime.h>
#include <cstdint>

// ---- static config ----
constexpr int B = 8, P = 8, N = 100, D = 256, H = 8, DK = 32, M = 64, KG = 16;
constexpr int L = P * N;      // 800
constexpr int NN = N * N;     // 10000
constexpr float PHI_SCALE = 0.8408964152537145f;  // (1/sqrt(0.25)) * 32^-0.25
constexpr float MINV = 0.125f;                    // 64^-0.5
constexpr int ADJ_SPLIT = 8;                      // split-K for adjfc MFMA GEMM
constexpr int KPAD = 10240;                       // 10000 padded to 8*1280 (40*32)

typedef __attribute__((ext_vector_type(8))) short short8v;  // 8 bf16
typedef __attribute__((ext_vector_type(4))) float f32x4;
typedef __attribute__((ext_vector_type(4))) unsigned short us4;

__device__ __forceinline__ unsigned short f2b(float f) {
    unsigned u = __float_as_uint(f);
    unsigned r = 0x7fffu + ((u >> 16) & 1u);
    return (unsigned short)((u + r) >> 16);
}

// ---- 0a. convert adj & fc_w to bf16, K-padded to 10240 ----
__global__ __launch_bounds__(256) void convert_kernel(
    const float* __restrict__ adj, const float* __restrict__ fcw,
    unsigned short* __restrict__ adjb, unsigned short* __restrict__ fcwb)
{
    const int col = blockIdx.x * 256 + threadIdx.x;   // 0..10239
    const int row = blockIdx.y;                       // 0..639
    if (row < 512) {
        float v = (col < NN) ? adj[(long)row * NN + col] : 0.f;
        adjb[(long)row * KPAD + col] = f2b(v);
    } else {
        const int r = row - 512;
        float v = (col < NN) ? fcw[(long)r * NN + col] : 0.f;
        fcwb[(long)r * KPAD + col] = f2b(v);
    }
}

// ---- 0b. convert x, Wq|Wk|Wv (concat), Wo to bf16 ----
__global__ __launch_bounds__(256) void convert_xw_kernel(
    const float* __restrict__ x, const float* __restrict__ Wq,
    const float* __restrict__ Wk, const float* __restrict__ Wv,
    const float* __restrict__ Wo,
    unsigned short* __restrict__ xb, unsigned short* __restrict__ wqkvb,
    unsigned short* __restrict__ wob)
{
    const int j = blockIdx.x * 256 + threadIdx.x;     // 0..1,900,543
    if (j < 1638400) {
        xb[j] = f2b(x[j]);
    } else if (j < 1703936) {
        wqkvb[j - 1638400] = f2b(Wq[j - 1638400]);
    } else if (j < 1769472) {
        wqkvb[j - 1638400] = f2b(Wk[j - 1703936]);
    } else if (j < 1835008) {
        wqkvb[j - 1638400] = f2b(Wv[j - 1769472]);
    } else {
        wob[j - 1835008] = f2b(Wo[j - 1835008]);
    }
}

// ---- 1. adjfc via MFMA: h1part[sp][r][c] partials of flat@fcw^T ----
__global__ __launch_bounds__(256) void adjfc_mfma_kernel(
    const unsigned short* __restrict__ adjb, const unsigned short* __restrict__ fcwb,
    float* __restrict__ h1part)
{
    const int task = blockIdx.x * 4 + (threadIdx.x >> 6);  // 2048 tasks
    const int kt = task & 7;
    const int nt = (task >> 3) & 7;
    const int mt = task >> 6;            // 0..31
    const int lane = threadIdx.x & 63;
    const int row = lane & 15;
    const int ko = (lane >> 4) * 8;
    const unsigned short* pa = adjb + (long)(mt * 16 + row) * KPAD + kt * 1280 + ko;
    const unsigned short* pb = fcwb + (long)(nt * 16 + row) * KPAD + kt * 1280 + ko;
    f32x4 acc = {0.f, 0.f, 0.f, 0.f};
    #pragma unroll 4
    for (int s = 0; s < 40; ++s) {
        short8v a = *reinterpret_cast<const short8v*>(pa);
        short8v b = *reinterpret_cast<const short8v*>(pb);
        acc = __builtin_amdgcn_mfma_f32_16x16x32_bf16(a, b, acc, 0, 0, 0);
        pa += 32; pb += 32;
    }
    const int c = nt * 16 + (lane & 15);
    const int rbase = mt * 16 + (lane >> 4) * 4;
    #pragma unroll
    for (int j = 0; j < 4; ++j) {
        int r = rbase + j;
        h1part[((long)kt * 512 + r) * 128 + c] = acc[j];
    }
}

// ---- 2. w = softmax over patch_len; absorbs split-reduce + bias + relu ----
__global__ __launch_bounds__(128) void wsm_kernel(
    const float* __restrict__ h1part, const float* __restrict__ fcb,
    const float* __restrict__ ow, const float* __restrict__ ob,
    float* __restrict__ wsm)
{
    __shared__ float part[8][2];
    const int bp = blockIdx.x;
    const int t = threadIdx.x;   // 128
    float owv = ow[t], bb = fcb[t];
    for (int pl = 0; pl < 8; ++pl) {
        float h = 0.f;
        for (int s = 0; s < ADJ_SPLIT; ++s)
            h += h1part[((long)s * 512 + bp * 8 + pl) * 128 + t];
        float v = fmaxf(h + bb, 0.f) * owv;
        #pragma unroll
        for (int off = 1; off < 64; off <<= 1) v += __shfl_xor(v, off);
        if ((t & 63) == 0) part[pl][t >> 6] = v;
    }
    __syncthreads();
    if (t == 0) {
        float lg[8], mx = -1e30f;
        for (int pl = 0; pl < 8; ++pl) {
            lg[pl] = part[pl][0] + part[pl][1] + ob[0];
            mx = fmaxf(mx, lg[pl]);
        }
        float s = 0.f;
        for (int pl = 0; pl < 8; ++pl) { lg[pl] = expf(lg[pl] - mx); s += lg[pl]; }
        for (int pl = 0; pl < 8; ++pl) wsm[bp * 8 + pl] = lg[pl] / s;
    }
}

// ---- 3. qkv via MFMA: [6400x256] @ [256x768] + bias ----
__global__ __launch_bounds__(256) void qkv_mfma_kernel(
    const unsigned short* __restrict__ xb, const unsigned short* __restrict__ wqkvb,
    const float* __restrict__ bq, const float* __restrict__ bk,
    const float* __restrict__ bv,
    float* __restrict__ q, float* __restrict__ k, float* __restrict__ v)
{
    const int task = blockIdx.x * 4 + (threadIdx.x >> 6);  // 19200 tasks
    const int nt = task % 48;
    const int mt = task / 48;            // 0..399
    const int lane = threadIdx.x & 63;
    const int row = lane & 15;
    const int ko = (lane >> 4) * 8;
    const unsigned short* pa = xb + (long)(mt * 16 + row) * 256 + ko;
    const unsigned short* pb = wqkvb + (long)(nt * 16 + row) * 256 + ko;
    f32x4 acc = {0.f, 0.f, 0.f, 0.f};
    #pragma unroll
    for (int s = 0; s < 8; ++s) {
        short8v a = *reinterpret_cast<const short8v*>(pa + s * 32);
        short8v b = *reinterpret_cast<const short8v*>(pb + s * 32);
        acc = __builtin_amdgcn_mfma_f32_16x16x32_bf16(a, b, acc, 0, 0, 0);
    }
    const int matid = nt >> 4;           // 0=q, 1=k, 2=v
    const int col = (nt & 15) * 16 + (lane & 15);
    float* outp = (matid == 0) ? q : ((matid == 1) ? k : v);
    const float* bp = (matid == 0) ? bq : ((matid == 1) ? bk : bv);
    const float bias = bp[col];
    const int rbase = mt * 16 + (lane >> 4) * 4;
    #pragma unroll
    for (int j = 0; j < 4; ++j)
        outp[(long)(rbase + j) * 256 + col] = acc[j] + bias;
}

// ---- 4. phi(q) and phi(k) pass1 in one kernel ----
__global__ __launch_bounds__(256) void phiqk_kernel(
    const float* __restrict__ qb, const float* __restrict__ kb,
    const float* __restrict__ proj,
    float* __restrict__ qp, float* __restrict__ ddout,
    float* __restrict__ diagout, float* __restrict__ partmax)
{
    __shared__ float ps[64 * 33];
    __shared__ float wmax[4];
    const int t = threadIdx.x;
    for (int j = t; j < 2048; j += 256) ps[(j >> 5) * 33 + (j & 31)] = proj[j];
    __syncthreads();
    const int bi = blockIdx.x;            // 3200: [0,1600) q, [1600,3200) k
    const bool isq = bi < 1600;
    const int rb = isq ? bi : bi - 1600;
    const int bh = rb / 25;
    const int b = bh >> 3, h = bh & 7;
    const int lbase = (rb % 25) * 32;
    const int wi = t >> 6;
    const int m = t & 63;
    const float* src = isq ? qb : kb;
    float rmax = -1e30f;
    for (int si = 0; si < 8; ++si) {
        const int l = lbase + si * 4 + wi;
        const float* ptr = src + (b * L + l) * 256 + h * 32;
        float dd = 0.f, diag = 0.f;
        #pragma unroll
        for (int d2 = 0; d2 < 32; ++d2) {
            float xv = ptr[d2] * PHI_SCALE;
            dd += xv * ps[m * 33 + d2];
            diag += xv * xv;
        }
        diag *= 0.5f;
        float s = dd;
        #pragma unroll
        for (int off = 1; off < 64; off <<= 1) s = fmaxf(s, __shfl_xor(s, off));
        const int group = (b * L + l) * 8 + h;
        if (isq) {
            qp[group * 64 + m] = MINV * (expf(dd - diag - s) + 1e-6f);
        } else {
            ddout[group * 64 + m] = dd;
            if (m == 0) diagout[group] = diag;
            rmax = fmaxf(rmax, s);
        }
    }
    if (!isq) {
        if (m == 0) wmax[wi] = rmax;
        __syncthreads();
        if (t == 0)
            partmax[rb] = fmaxf(fmaxf(wmax[0], wmax[1]), fmaxf(wmax[2], wmax[3]));
    }
}

// ---- 4b. reduce 25 partials -> kmax[bh] ----
__global__ __launch_bounds__(64) void kmax_kernel(
    const float* __restrict__ partmax, float* __restrict__ kmax)
{
    const int bh = blockIdx.x;
    const int t = threadIdx.x;
    float s = (t < 25) ? partmax[bh * 25 + t] : -1e30f;
    #pragma unroll
    for (int off = 1; off < 64; off <<= 1) s = fmaxf(s, __shfl_xor(s, off));
    if (t == 0) kmax[bh] = s;
}

// ---- 5. kvs partials: 256-thr blocks, k-quarters for uniform occupancy ----
__global__ __launch_bounds__(256) void kvs_kernel(
    const float* __restrict__ dd, const float* __restrict__ diagk,
    const float* __restrict__ kmax, const float* __restrict__ vb,
    const float* __restrict__ gum,
    float* __restrict__ kvspart, float* __restrict__ ksumpart, int nsplit)
{
    constexpr int TL = 64;
    __shared__ float kps[TL][64];
    __shared__ float vs[TL][32];
    __shared__ float egs[TL][4];
    const int bi = blockIdx.x;            // 64 * nsplit * 4
    const int kq4 = bi & 3;
    const int sp = (bi >> 2) % nsplit;
    const int bh = bi / (4 * nsplit);
    const int b = bh >> 3, h = bh & 7;
    const int lstart = sp * L / nsplit;
    const int lend = (sp + 1) * L / nsplit;
    const int t = threadIdx.x;
    const int kw = t >> 6;                // wave 0..3 -> k within quarter
    const int mg = (t >> 3) & 7;
    const int dg = t & 7;
    const float stab = kmax[bh];
    float acc[8][4];
    #pragma unroll
    for (int i = 0; i < 8; ++i)
        for (int j = 0; j < 4; ++j) acc[i][j] = 0.f;
    float sacc[8] = {0, 0, 0, 0, 0, 0, 0, 0};
    for (int l0 = lstart; l0 < lend; l0 += TL) {
        const int chunk = min(TL, lend - l0);
        __syncthreads();
        for (int j = t; j < chunk * 64; j += 256) {
            int ll = j >> 6, m = j & 63;
            int g = (b * L + l0 + ll) * 8 + h;
            kps[ll][m] = MINV * (expf(dd[g * 64 + m] - diagk[g] - stab) + 1e-6f);
        }
        for (int j = t; j < chunk * 32; j += 256) {
            int ll = j >> 5;
            vs[ll][j & 31] = vb[(b * L + l0 + ll) * 256 + h * 32 + (j & 31)];
        }
        for (int j = t; j < chunk * 4; j += 256) {
            int ll = j >> 2;
            egs[ll][j & 3] = expf(gum[((b * L + l0 + ll) * 8 + h) * 16 + kq4 * 4 + (j & 3)]);
        }
        __syncthreads();
        #pragma unroll 2
        for (int ll = 0; ll < chunk; ++ll) {
            float egv = egs[ll][kw];
            const float4* kr = reinterpret_cast<const float4*>(&kps[ll][mg * 8]);
            float4 ka = kr[0], kb4 = kr[1];
            float4 v4 = *reinterpret_cast<const float4*>(&vs[ll][dg * 4]);
            float s[8];
            s[0] = ka.x * egv;  s[1] = ka.y * egv;  s[2] = ka.z * egv;  s[3] = ka.w * egv;
            s[4] = kb4.x * egv; s[5] = kb4.y * egv; s[6] = kb4.z * egv; s[7] = kb4.w * egv;
            #pragma unroll
            for (int mi = 0; mi < 8; ++mi) {
                acc[mi][0] += s[mi] * v4.x;
                acc[mi][1] += s[mi] * v4.y;
                acc[mi][2] += s[mi] * v4.z;
                acc[mi][3] += s[mi] * v4.w;
            }
            if (dg == 0) {
                #pragma unroll
                for (int mi = 0; mi < 8; ++mi) sacc[mi] += s[mi];
            }
        }
    }
    const int k = kq4 * 4 + kw;
    float* kbase = kvspart + (((long)(sp * 64 + bh) * 16 + k) * 64 + mg * 8) * 32 + dg * 4;
    #pragma unroll
    for (int mi = 0; mi < 8; ++mi)
        *reinterpret_cast<float4*>(kbase + mi * 32) =
            make_float4(acc[mi][0], acc[mi][1], acc[mi][2], acc[mi][3]);
    if (dg == 0) {
        float* sb = ksumpart + ((long)(sp * 64 + bh) * 16 + k) * 64 + mg * 8;
        #pragma unroll
        for (int mi = 0; mi < 8; ++mi) sb[mi] = sacc[mi];
    }
}

// ---- 5b. reduce split partials ----
__global__ __launch_bounds__(256) void kvsreduce_kernel(
    const float* __restrict__ kvspart, const float* __restrict__ ksumpart,
    float* __restrict__ kvs, float* __restrict__ ksum, int nsplit)
{
    constexpr int NKVS4 = 2097152 / 4;
    constexpr int NKS = 65536;
    const int idx = blockIdx.x * 256 + threadIdx.x;
    if (idx < NKVS4) {
        const float4* p = reinterpret_cast<const float4*>(kvspart) + idx;
        float4 a = p[0];
        for (int s = 1; s < nsplit; ++s) {
            float4 b4 = p[(long)s * NKVS4];
            a.x += b4.x; a.y += b4.y; a.z += b4.z; a.w += b4.w;
        }
        reinterpret_cast<float4*>(kvs)[idx] = a;
    } else if (idx < NKVS4 + NKS) {
        int j = idx - NKVS4;
        float s = ksumpart[j];
        for (int sp = 1; sp < nsplit; ++sp) s += ksumpart[(long)sp * NKS + j];
        ksum[j] = s;
    }
}

// ---- 6. z = LN(mean_k (qp.kvs)*invden) — 40 rows/block for occupancy ----
__global__ __launch_bounds__(320) void z_kernel(
    const float* __restrict__ qp, const float* __restrict__ kvs,
    const float* __restrict__ ksum, const float* __restrict__ ln_g,
    const float* __restrict__ ln_b, float* __restrict__ z)
{
    __shared__ float qps[40][65];     // bank=(r+m)%32, conflict-free
    __shared__ float kvss[2048];
    __shared__ float ksums[16][65];
    __shared__ float invden[40][17];
    const int bi = blockIdx.x;        // 1280
    const int bh = bi / 20;
    const int b = bh >> 3, h = bh & 7;
    const int l0 = (bi % 20) * 40;
    const int t = threadIdx.x;        // 320
    for (int j = t; j < 40 * 64; j += 320) {
        int ll = j >> 6;
        qps[ll][j & 63] = qp[((b * L + l0 + ll) * 8 + h) * 64 + (j & 63)];
    }
    for (int j = t; j < 16 * 64; j += 320)
        ksums[j >> 6][j & 63] = ksum[(long)bh * 1024 + j];
    __syncthreads();
    for (int j = t; j < 40 * 16; j += 320) {
        int ll = j >> 4, kk = j & 15;
        float s = 0.f;
        #pragma unroll 8
        for (int m = 0; m < 64; ++m) s += qps[ll][m] * ksums[kk][m];
        invden[ll][kk] = 1.0f / (s + 1e-8f);
    }
    const int lr = t >> 3;            // 0..39 (row)
    const int dg = t & 7;
    float acc[4] = {0, 0, 0, 0};
    for (int kk = 0; kk < 16; ++kk) {
        __syncthreads();
        const float4* src = reinterpret_cast<const float4*>(kvs + ((long)bh * 16 + kk) * 2048);
        for (int j = t; j < 512; j += 320)
            reinterpret_cast<float4*>(kvss)[j] = src[j];
        __syncthreads();
        float n[4] = {0, 0, 0, 0};
        #pragma unroll 4
        for (int m = 0; m < 64; ++m) {
            float4 k4 = *reinterpret_cast<const float4*>(&kvss[m * 32 + dg * 4]);
            float qv = qps[lr][m];
            n[0] += qv * k4.x; n[1] += qv * k4.y; n[2] += qv * k4.z; n[3] += qv * k4.w;
        }
        float iv = invden[lr][kk];
        #pragma unroll
        for (int j = 0; j < 4; ++j) acc[j] += n[j] * iv;
    }
    const float4 g4 = reinterpret_cast<const float4*>(ln_g)[dg];
    const float4 b4 = reinterpret_cast<const float4*>(ln_b)[dg];
    float zv[4];
    float s1 = 0.f, s2 = 0.f;
    #pragma unroll
    for (int j = 0; j < 4; ++j) {
        zv[j] = acc[j] * (1.0f / 16.0f);
        s1 += zv[j]; s2 += zv[j] * zv[j];
    }
    #pragma unroll
    for (int off = 1; off < 8; off <<= 1) {
        s1 += __shfl_xor(s1, off);
        s2 += __shfl_xor(s2, off);
    }
    float mu = s1 * (1.0f / 32.0f);
    float var = s2 * (1.0f / 32.0f) - mu * mu;
    float rs = rsqrtf(var + 1e-5f);
    float4 o;
    o.x = (zv[0] - mu) * rs * g4.x + b4.x;
    o.y = (zv[1] - mu) * rs * g4.y + b4.y;
    o.z = (zv[2] - mu) * rs * g4.z + b4.z;
    o.w = (zv[3] - mu) * rs * g4.w + b4.w;
    *reinterpret_cast<float4*>(&z[(b * L + l0 + lr) * 256 + h * 32 + dg * 4]) = o;
}

// ---- 7. fused + row L1-normalize ----
__global__ __launch_bounds__(128) void fused_kernel(
    const float* __restrict__ adj, const float* __restrict__ wsm,
    float* __restrict__ fusedn)
{
    __shared__ float part[2];
    const int bi = blockIdx.x;
    const int b = bi / 800;
    const int p = (bi / 100) & 7;
    const int i = bi % 100;
    const int t = threadIdx.x;
    float f = 0.f;
    if (t < 100) {
        #pragma unroll
        for (int pl = 0; pl < 8; ++pl)
            f += adj[((long)(b * 64 + p * 8 + pl)) * NN + i * 100 + t] * wsm[(b * 8 + p) * 8 + pl];
    }
    float a = fabsf(f);
    #pragma unroll
    for (int off = 1; off < 64; off <<= 1) a += __shfl_xor(a, off);
    if ((t & 63) == 0) part[t >> 6] = a;
    __syncthreads();
    float denom = fmaxf(part[0] + part[1], 1e-12f);
    if (t < 100) fusedn[(long)bi * 100 + t] = f / denom;
}

// ---- 8. zb16 = bf16(z + block-diag(fusedn) @ v)  (fused convert) ----
__global__ __launch_bounds__(256) void bias_kernel(
    const float* __restrict__ fusedn, const float* __restrict__ vb,
    const float* __restrict__ z, unsigned short* __restrict__ zb16)
{
    __shared__ float fs[10 * 100];
    const int bi = blockIdx.x;
    const int bp = bi / 10;
    const int b = bp >> 3, p = bp & 7;
    const int i0 = (bi % 10) * 10;
    const int t = threadIdx.x;
    for (int j = t; j < 1000; j += 256)
        fs[j] = fusedn[(long)bp * 10000 + i0 * 100 + j];
    __syncthreads();
    float acc[10];
    #pragma unroll
    for (int r = 0; r < 10; ++r) acc[r] = 0.f;
    for (int j = 0; j < 100; ++j) {
        float vj = vb[(b * 800 + p * 100 + j) * 256 + t];
        #pragma unroll
        for (int r = 0; r < 10; ++r)
            acc[r] += fs[r * 100 + j] * vj;
    }
    for (int r = 0; r < 10; ++r) {
        const long idx = (long)(b * 800 + p * 100 + i0 + r) * 256 + t;
        zb16[idx] = f2b(z[idx] + acc[r]);
    }
}

// ---- 9. out via MFMA: [6400x256] @ [256x256] + bias ----
__global__ __launch_bounds__(256) void out_mfma_kernel(
    const unsigned short* __restrict__ zb, const unsigned short* __restrict__ wob,
    const float* __restrict__ bo, float* __restrict__ out)
{
    const int task = blockIdx.x * 4 + (threadIdx.x >> 6);  // 6400 tasks
    const int nt = task & 15;
    const int mt = task >> 4;            // 0..399
    const int lane = threadIdx.x & 63;
    const int row = lane & 15;
    const int ko = (lane >> 4) * 8;
    const unsigned short* pa = zb + (long)(mt * 16 + row) * 256 + ko;
    const unsigned short* pb = wob + (long)(nt * 16 + row) * 256 + ko;
    f32x4 acc = {0.f, 0.f, 0.f, 0.f};
    #pragma unroll
    for (int s = 0; s < 8; ++s) {
        short8v a = *reinterpret_cast<const short8v*>(pa + s * 32);
        short8v b = *reinterpret_cast<const short8v*>(pb + s * 32);
        acc = __builtin_amdgcn_mfma_f32_16x16x32_bf16(a, b, acc, 0, 0, 0);
    }
    const int col = nt * 16 + (lane & 15);
    const float bias = bo[col];
    const int rbase = mt * 16 + (lane >> 4) * 4;
    #pragma unroll
    for (int j = 0; j < 4; ++j)
        out[(long)(rbase + j) * 256 + col] = acc[j] + bias;
}

extern "C" void kernel_launch(void* const* d_in, const int* in_sizes, int n_in,
                              void* d_out, int out_size, void* d_ws, size_t ws_size,
                              hipStream_t stream) {
    const float* x     = (const float*)d_in[0];
    const float* adj   = (const float*)d_in[1];
    const float* Wq_w  = (const float*)d_in[2];
    const float* Wq_b  = (const float*)d_in[3];
    const float* Wk_w  = (const float*)d_in[4];
    const float* Wk_b  = (const float*)d_in[5];
    const float* Wv_w  = (const float*)d_in[6];
    const float* Wv_b  = (const float*)d_in[7];
    const float* Wo_w  = (const float*)d_in[8];
    const float* Wo_b  = (const float*)d_in[9];
    const float* ln_g  = (const float*)d_in[10];
    const float* ln_b  = (const float*)d_in[11];
    const float* fc_w  = (const float*)d_in[12];
    const float* fc_b  = (const float*)d_in[13];
    const float* out_w = (const float*)d_in[14];
    const float* out_b = (const float*)d_in[15];
    const float* proj  = (const float*)d_in[16];
    const float* gum   = (const float*)d_in[17];
    float* out = (float*)d_out;

    // ---- workspace layout (float units) — overlay tenants, disjoint lifetimes ----
    float* ws = (float*)d_ws;
    const size_t wsfl = ws_size / sizeof(float);
    constexpr size_t AFTER_NEED = 11260032;
    const int nsplit = (wsfl >= (size_t)6 * 2162688 + AFTER_NEED) ? 6 : 3;
    const size_t OVL = (size_t)nsplit * 2162688;

    float* ovl = ws;
    unsigned short* adjb = (unsigned short*)ovl;              // 512*10240 bf16
    unsigned short* fcwb = (unsigned short*)(ovl + 2621440);  // 128*10240 bf16
    float* h1part  = ovl + 3276800;       // 524,288
    float* qbuf    = ovl;                 // 1,638,400
    float* kbuf    = ovl + 1638400;       // 1,638,400
    unsigned short* xb    = (unsigned short*)(ovl + 3276800); // 1,638,400 bf16
    unsigned short* wqkvb = (unsigned short*)(ovl + 4096000); // 196,608 bf16
    float* kvspart = ovl;                 // nsplit * 2,097,152
    float* ksumpart= ovl + (size_t)nsplit * 2097152;  // nsplit * 65,536
    float* zbuf    = ovl;                 // 1,638,400
    float* fusedn  = ovl + 1638400;       // 640,000

    float* after   = ws + OVL;
    float* vbuf    = after;               // 1,638,400
    float* qp      = vbuf + 1638400;      // 3,276,800
    float* kp      = qp + 3276800;        // 3,276,800 (raw dd for keys)
    float* diagk   = kp + 3276800;        // 51,200
    float* kvs     = diagk + 51200;       // 2,097,152
    float* ksum    = kvs + 2097152;       // 65,536
    float* wsm     = ksum + 65536;        // 512
    float* partmax = wsm + 512;           // 1,600
    float* kmax    = partmax + 1600;      // 64
    unsigned short* wob  = (unsigned short*)(kmax + 64);      // 65,536 bf16
    unsigned short* zb16 = (unsigned short*)(kmax + 64 + 32768); // 1,638,400 bf16

    // adj path first so t1 tenants die before qkv
    convert_kernel<<<dim3(40, 640), 256, 0, stream>>>(adj, fc_w, adjb, fcwb);
    adjfc_mfma_kernel<<<512, 256, 0, stream>>>(adjb, fcwb, h1part);
    wsm_kernel<<<64, 128, 0, stream>>>(h1part, fc_b, out_w, out_b, wsm);

    convert_xw_kernel<<<7424, 256, 0, stream>>>(x, Wq_w, Wk_w, Wv_w, Wo_w,
                                                xb, wqkvb, wob);
    qkv_mfma_kernel<<<4800, 256, 0, stream>>>(xb, wqkvb, Wq_b, Wk_b, Wv_b,
                                              qbuf, kbuf, vbuf);
    phiqk_kernel<<<3200, 256, 0, stream>>>(qbuf, kbuf, proj, qp, kp, diagk, partmax);
    kmax_kernel<<<64, 64, 0, stream>>>(partmax, kmax);
    kvs_kernel<<<64 * nsplit * 4, 256, 0, stream>>>(kp, diagk, kmax, vbuf, gum,
                                                    kvspart, ksumpart, nsplit);
    kvsreduce_kernel<<<2304, 256, 0, stream>>>(kvspart, ksumpart, kvs, ksum, nsplit);
    z_kernel<<<1280, 320, 0, stream>>>(qp, kvs, ksum, ln_g, ln_b, zbuf);
    fused_kernel<<<6400, 128, 0, stream>>>(adj, wsm, fusedn);
    bias_kernel<<<640, 256, 0, stream>>>(fusedn, vbuf, zbuf, zb16);
    out_mfma_kernel<<<1600, 256, 0, stream>>>(zb16, wob, Wo_b, out);
}

// Round 11
// 395.598 us; speedup vs baseline: 1.2765x; 1.2765x over previous
//
#include <hip/hip_runtime.h>
#include <cstdint>

// ---- static config ----
constexpr int B = 8, P = 8, N = 100, D = 256, H = 8, DK = 32, M = 64, KG = 16;
constexpr int L = P * N;      // 800
constexpr int NN = N * N;     // 10000
constexpr float PHI_SCALE = 0.8408964152537145f;  // (1/sqrt(0.25)) * 32^-0.25
constexpr float MINV = 0.125f;                    // 64^-0.5
constexpr int ADJ_SPLIT = 8;                      // split-K for adjfc MFMA GEMM
constexpr int KPAD = 10240;                       // 10000 padded to 8*1280 (40*32)

typedef __attribute__((ext_vector_type(8))) short short8v;  // 8 bf16
typedef __attribute__((ext_vector_type(4))) float f32x4;
typedef __attribute__((ext_vector_type(4))) unsigned short us4;

__device__ __forceinline__ unsigned short f2b(float f) {
    unsigned u = __float_as_uint(f);
    unsigned r = 0x7fffu + ((u >> 16) & 1u);
    return (unsigned short)((u + r) >> 16);
}

// ---- 0a. convert adj & fc_w to bf16, K-padded to 10240 ----
__global__ __launch_bounds__(256) void convert_kernel(
    const float* __restrict__ adj, const float* __restrict__ fcw,
    unsigned short* __restrict__ adjb, unsigned short* __restrict__ fcwb)
{
    const int col = blockIdx.x * 256 + threadIdx.x;   // 0..10239
    const int row = blockIdx.y;                       // 0..639
    if (row < 512) {
        float v = (col < NN) ? adj[(long)row * NN + col] : 0.f;
        adjb[(long)row * KPAD + col] = f2b(v);
    } else {
        const int r = row - 512;
        float v = (col < NN) ? fcw[(long)r * NN + col] : 0.f;
        fcwb[(long)r * KPAD + col] = f2b(v);
    }
}

// ---- 0b. convert x, Wq|Wk|Wv (concat), Wo to bf16 ----
__global__ __launch_bounds__(256) void convert_xw_kernel(
    const float* __restrict__ x, const float* __restrict__ Wq,
    const float* __restrict__ Wk, const float* __restrict__ Wv,
    const float* __restrict__ Wo,
    unsigned short* __restrict__ xb, unsigned short* __restrict__ wqkvb,
    unsigned short* __restrict__ wob)
{
    const int j = blockIdx.x * 256 + threadIdx.x;     // 0..1,900,543
    if (j < 1638400) {
        xb[j] = f2b(x[j]);
    } else if (j < 1703936) {
        wqkvb[j - 1638400] = f2b(Wq[j - 1638400]);
    } else if (j < 1769472) {
        wqkvb[j - 1638400] = f2b(Wk[j - 1703936]);
    } else if (j < 1835008) {
        wqkvb[j - 1638400] = f2b(Wv[j - 1769472]);
    } else {
        wob[j - 1835008] = f2b(Wo[j - 1835008]);
    }
}

// ---- 1. adjfc via MFMA ----
__global__ __launch_bounds__(256) void adjfc_mfma_kernel(
    const unsigned short* __restrict__ adjb, const unsigned short* __restrict__ fcwb,
    float* __restrict__ h1part)
{
    const int task = blockIdx.x * 4 + (threadIdx.x >> 6);  // 2048 tasks
    const int kt = task & 7;
    const int nt = (task >> 3) & 7;
    const int mt = task >> 6;            // 0..31
    const int lane = threadIdx.x & 63;
    const int row = lane & 15;
    const int ko = (lane >> 4) * 8;
    const unsigned short* pa = adjb + (long)(mt * 16 + row) * KPAD + kt * 1280 + ko;
    const unsigned short* pb = fcwb + (long)(nt * 16 + row) * KPAD + kt * 1280 + ko;
    f32x4 acc = {0.f, 0.f, 0.f, 0.f};
    #pragma unroll 4
    for (int s = 0; s < 40; ++s) {
        short8v a = *reinterpret_cast<const short8v*>(pa);
        short8v b = *reinterpret_cast<const short8v*>(pb);
        acc = __builtin_amdgcn_mfma_f32_16x16x32_bf16(a, b, acc, 0, 0, 0);
        pa += 32; pb += 32;
    }
    const int c = nt * 16 + (lane & 15);
    const int rbase = mt * 16 + (lane >> 4) * 4;
    #pragma unroll
    for (int j = 0; j < 4; ++j) {
        int r = rbase + j;
        h1part[((long)kt * 512 + r) * 128 + c] = acc[j];
    }
}

// ---- 2. w = softmax over patch_len; absorbs split-reduce + bias + relu ----
__global__ __launch_bounds__(128) void wsm_kernel(
    const float* __restrict__ h1part, const float* __restrict__ fcb,
    const float* __restrict__ ow, const float* __restrict__ ob,
    float* __restrict__ wsm)
{
    __shared__ float part[8][2];
    const int bp = blockIdx.x;
    const int t = threadIdx.x;   // 128
    float owv = ow[t], bb = fcb[t];
    for (int pl = 0; pl < 8; ++pl) {
        float h = 0.f;
        for (int s = 0; s < ADJ_SPLIT; ++s)
            h += h1part[((long)s * 512 + bp * 8 + pl) * 128 + t];
        float v = fmaxf(h + bb, 0.f) * owv;
        #pragma unroll
        for (int off = 1; off < 64; off <<= 1) v += __shfl_xor(v, off);
        if ((t & 63) == 0) part[pl][t >> 6] = v;
    }
    __syncthreads();
    if (t == 0) {
        float lg[8], mx = -1e30f;
        for (int pl = 0; pl < 8; ++pl) {
            lg[pl] = part[pl][0] + part[pl][1] + ob[0];
            mx = fmaxf(mx, lg[pl]);
        }
        float s = 0.f;
        for (int pl = 0; pl < 8; ++pl) { lg[pl] = expf(lg[pl] - mx); s += lg[pl]; }
        for (int pl = 0; pl < 8; ++pl) wsm[bp * 8 + pl] = lg[pl] / s;
    }
}

// ---- 3. qkv via MFMA: [6400x256] @ [256x768] + bias ----
__global__ __launch_bounds__(256) void qkv_mfma_kernel(
    const unsigned short* __restrict__ xb, const unsigned short* __restrict__ wqkvb,
    const float* __restrict__ bq, const float* __restrict__ bk,
    const float* __restrict__ bv,
    float* __restrict__ q, float* __restrict__ k, float* __restrict__ v)
{
    const int task = blockIdx.x * 4 + (threadIdx.x >> 6);  // 19200 tasks
    const int nt = task % 48;
    const int mt = task / 48;            // 0..399
    const int lane = threadIdx.x & 63;
    const int row = lane & 15;
    const int ko = (lane >> 4) * 8;
    const unsigned short* pa = xb + (long)(mt * 16 + row) * 256 + ko;
    const unsigned short* pb = wqkvb + (long)(nt * 16 + row) * 256 + ko;
    f32x4 acc = {0.f, 0.f, 0.f, 0.f};
    #pragma unroll
    for (int s = 0; s < 8; ++s) {
        short8v a = *reinterpret_cast<const short8v*>(pa + s * 32);
        short8v b = *reinterpret_cast<const short8v*>(pb + s * 32);
        acc = __builtin_amdgcn_mfma_f32_16x16x32_bf16(a, b, acc, 0, 0, 0);
    }
    const int matid = nt >> 4;           // 0=q, 1=k, 2=v
    const int col = (nt & 15) * 16 + (lane & 15);
    float* outp = (matid == 0) ? q : ((matid == 1) ? k : v);
    const float* bp = (matid == 0) ? bq : ((matid == 1) ? bk : bv);
    const float bias = bp[col];
    const int rbase = mt * 16 + (lane >> 4) * 4;
    #pragma unroll
    for (int j = 0; j < 4; ++j)
        outp[(long)(rbase + j) * 256 + col] = acc[j] + bias;
}

// ---- 4. phi(q) and phi(k) pass1; qp emitted as bf16 for MFMA consumption ----
__global__ __launch_bounds__(256) void phiqk_kernel(
    const float* __restrict__ qb, const float* __restrict__ kb,
    const float* __restrict__ proj,
    unsigned short* __restrict__ qpb, float* __restrict__ ddout,
    float* __restrict__ diagout, float* __restrict__ partmax)
{
    __shared__ float ps[64 * 33];
    __shared__ float wmax[4];
    const int t = threadIdx.x;
    for (int j = t; j < 2048; j += 256) ps[(j >> 5) * 33 + (j & 31)] = proj[j];
    __syncthreads();
    const int bi = blockIdx.x;            // 3200: [0,1600) q, [1600,3200) k
    const bool isq = bi < 1600;
    const int rb = isq ? bi : bi - 1600;
    const int bh = rb / 25;
    const int b = bh >> 3, h = bh & 7;
    const int lbase = (rb % 25) * 32;
    const int wi = t >> 6;
    const int m = t & 63;
    const float* src = isq ? qb : kb;
    float rmax = -1e30f;
    for (int si = 0; si < 8; ++si) {
        const int l = lbase + si * 4 + wi;
        const float* ptr = src + (b * L + l) * 256 + h * 32;
        float dd = 0.f, diag = 0.f;
        #pragma unroll
        for (int d2 = 0; d2 < 32; ++d2) {
            float xv = ptr[d2] * PHI_SCALE;
            dd += xv * ps[m * 33 + d2];
            diag += xv * xv;
        }
        diag *= 0.5f;
        float s = dd;
        #pragma unroll
        for (int off = 1; off < 64; off <<= 1) s = fmaxf(s, __shfl_xor(s, off));
        const int group = (b * L + l) * 8 + h;
        if (isq) {
            qpb[group * 64 + m] = f2b(MINV * (expf(dd - diag - s) + 1e-6f));
        } else {
            ddout[group * 64 + m] = dd;
            if (m == 0) diagout[group] = diag;
            rmax = fmaxf(rmax, s);
        }
    }
    if (!isq) {
        if (m == 0) wmax[wi] = rmax;
        __syncthreads();
        if (t == 0)
            partmax[rb] = fmaxf(fmaxf(wmax[0], wmax[1]), fmaxf(wmax[2], wmax[3]));
    }
}

// ---- 4b. reduce 25 partials -> kmax[bh] ----
__global__ __launch_bounds__(64) void kmax_kernel(
    const float* __restrict__ partmax, float* __restrict__ kmax)
{
    const int bh = blockIdx.x;
    const int t = threadIdx.x;
    float s = (t < 25) ? partmax[bh * 25 + t] : -1e30f;
    #pragma unroll
    for (int off = 1; off < 64; off <<= 1) s = fmaxf(s, __shfl_xor(s, off));
    if (t == 0) kmax[bh] = s;
}

// ---- 5. kvs partials: output TRANSPOSED [k][d][m] for z-MFMA B-layout ----
__global__ __launch_bounds__(256) void kvs_kernel(
    const float* __restrict__ dd, const float* __restrict__ diagk,
    const float* __restrict__ kmax, const float* __restrict__ vb,
    const float* __restrict__ gum,
    float* __restrict__ kvspart, float* __restrict__ ksumpart, int nsplit)
{
    constexpr int TL = 64;
    __shared__ float kps[TL][64];
    __shared__ float vs[TL][32];
    __shared__ float egs[TL][4];
    const int bi = blockIdx.x;            // 64 * nsplit * 4
    const int kq4 = bi & 3;
    const int sp = (bi >> 2) % nsplit;
    const int bh = bi / (4 * nsplit);
    const int b = bh >> 3, h = bh & 7;
    const int lstart = sp * L / nsplit;
    const int lend = (sp + 1) * L / nsplit;
    const int t = threadIdx.x;
    const int kw = t >> 6;                // wave 0..3 -> k within quarter
    const int mg = (t >> 3) & 7;
    const int dg = t & 7;
    const float stab = kmax[bh];
    float acc[8][4];
    #pragma unroll
    for (int i = 0; i < 8; ++i)
        for (int j = 0; j < 4; ++j) acc[i][j] = 0.f;
    float sacc[8] = {0, 0, 0, 0, 0, 0, 0, 0};
    for (int l0 = lstart; l0 < lend; l0 += TL) {
        const int chunk = min(TL, lend - l0);
        __syncthreads();
        for (int j = t; j < chunk * 64; j += 256) {
            int ll = j >> 6, m = j & 63;
            int g = (b * L + l0 + ll) * 8 + h;
            kps[ll][m] = MINV * (expf(dd[g * 64 + m] - diagk[g] - stab) + 1e-6f);
        }
        for (int j = t; j < chunk * 32; j += 256) {
            int ll = j >> 5;
            vs[ll][j & 31] = vb[(b * L + l0 + ll) * 256 + h * 32 + (j & 31)];
        }
        for (int j = t; j < chunk * 4; j += 256) {
            int ll = j >> 2;
            egs[ll][j & 3] = expf(gum[((b * L + l0 + ll) * 8 + h) * 16 + kq4 * 4 + (j & 3)]);
        }
        __syncthreads();
        #pragma unroll 2
        for (int ll = 0; ll < chunk; ++ll) {
            float egv = egs[ll][kw];
            const float4* kr = reinterpret_cast<const float4*>(&kps[ll][mg * 8]);
            float4 ka = kr[0], kb4 = kr[1];
            float4 v4 = *reinterpret_cast<const float4*>(&vs[ll][dg * 4]);
            float s[8];
            s[0] = ka.x * egv;  s[1] = ka.y * egv;  s[2] = ka.z * egv;  s[3] = ka.w * egv;
            s[4] = kb4.x * egv; s[5] = kb4.y * egv; s[6] = kb4.z * egv; s[7] = kb4.w * egv;
            #pragma unroll
            for (int mi = 0; mi < 8; ++mi) {
                acc[mi][0] += s[mi] * v4.x;
                acc[mi][1] += s[mi] * v4.y;
                acc[mi][2] += s[mi] * v4.z;
                acc[mi][3] += s[mi] * v4.w;
            }
            if (dg == 0) {
                #pragma unroll
                for (int mi = 0; mi < 8; ++mi) sacc[mi] += s[mi];
            }
        }
    }
    const int k = kq4 * 4 + kw;
    // transposed: kvspart[sp][bh][k][d][m]
    float* kbase = kvspart + ((long)(sp * 64 + bh) * 16 + k) * 2048;
    #pragma unroll
    for (int j = 0; j < 4; ++j) {
        const int d = dg * 4 + j;
        *reinterpret_cast<float4*>(kbase + d * 64 + mg * 8) =
            make_float4(acc[0][j], acc[1][j], acc[2][j], acc[3][j]);
        *reinterpret_cast<float4*>(kbase + d * 64 + mg * 8 + 4) =
            make_float4(acc[4][j], acc[5][j], acc[6][j], acc[7][j]);
    }
    if (dg == 0) {
        float* sb = ksumpart + ((long)(sp * 64 + bh) * 16 + k) * 64 + mg * 8;
        #pragma unroll
        for (int mi = 0; mi < 8; ++mi) sb[mi] = sacc[mi];
    }
}

// ---- 5b. reduce split partials -> bf16 kvsb[bh][k*32+d][m], ksumb[bh][k][m] ----
__global__ __launch_bounds__(256) void kvsreduce_kernel(
    const float* __restrict__ kvspart, const float* __restrict__ ksumpart,
    unsigned short* __restrict__ kvsb, unsigned short* __restrict__ ksumb, int nsplit)
{
    constexpr int NKVS4 = 524288;     // 2,097,152 floats / 4
    constexpr int NKS4 = 16384;       // 65,536 floats / 4
    const int idx = blockIdx.x * 256 + threadIdx.x;   // 2112 blocks
    if (idx < NKVS4) {
        const float4* p = reinterpret_cast<const float4*>(kvspart) + idx;
        float4 a = p[0];
        for (int s = 1; s < nsplit; ++s) {
            float4 b4 = p[(long)s * NKVS4];
            a.x += b4.x; a.y += b4.y; a.z += b4.z; a.w += b4.w;
        }
        us4 o = { f2b(a.x), f2b(a.y), f2b(a.z), f2b(a.w) };
        reinterpret_cast<us4*>(kvsb)[idx] = o;
    } else if (idx < NKVS4 + NKS4) {
        int j = idx - NKVS4;
        const float4* p = reinterpret_cast<const float4*>(ksumpart) + j;
        float4 a = p[0];
        for (int s = 1; s < nsplit; ++s) {
            float4 b4 = p[(long)s * NKS4];
            a.x += b4.x; a.y += b4.y; a.z += b4.z; a.w += b4.w;
        }
        us4 o = { f2b(a.x), f2b(a.y), f2b(a.z), f2b(a.w) };
        reinterpret_cast<us4*>(ksumb)[j] = o;
    }
}

// ---- 6. z via MFMA: num GEMM [16 rows x 512 kd] per block; den MFMA; LN ----
__global__ __launch_bounds__(256) void z_mfma_kernel(
    const unsigned short* __restrict__ qpb, const unsigned short* __restrict__ kvsb,
    const unsigned short* __restrict__ ksumb, const float* __restrict__ ln_g,
    const float* __restrict__ ln_b, float* __restrict__ z)
{
    __shared__ float invden[16][17];
    __shared__ float psum[4][16][33];
    const int bi = blockIdx.x;        // 3200 = 64 bh * 50 row-tiles
    const int bh = bi / 50;
    const int rt = bi % 50;
    const int b = bh >> 3, h = bh & 7;
    const int t = threadIdx.x;
    const int w = t >> 6;
    const int lane = t & 63;
    const int c = lane & 15;
    const int ko = (lane >> 4) * 8;
    // A fragments: qp rows of this tile (row = c)
    const int l = rt * 16 + c;
    const unsigned short* arow = qpb + ((long)(b * L + l) * 8 + h) * 64;
    short8v a0 = *reinterpret_cast<const short8v*>(arow + ko);
    short8v a1 = *reinterpret_cast<const short8v*>(arow + ko + 32);
    // den: [16 rows] x [16 k], K=64 over m; B = ksumb[bh][k][m] (col-major-K layout)
    if (w == 0) {
        const unsigned short* krow = ksumb + (long)bh * 1024 + c * 64;
        short8v k0 = *reinterpret_cast<const short8v*>(krow + ko);
        short8v k1 = *reinterpret_cast<const short8v*>(krow + ko + 32);
        f32x4 dacc = {0.f, 0.f, 0.f, 0.f};
        dacc = __builtin_amdgcn_mfma_f32_16x16x32_bf16(a0, k0, dacc, 0, 0, 0);
        dacc = __builtin_amdgcn_mfma_f32_16x16x32_bf16(a1, k1, dacc, 0, 0, 0);
        #pragma unroll
        for (int j = 0; j < 4; ++j)
            invden[(lane >> 4) * 4 + j][c] = 1.0f / (dacc[j] + 1e-8f);
    }
    __syncthreads();
    // num: wave w handles col-tiles w*8 .. w*8+7 (cols = kd = k*32+d)
    const unsigned short* Bbase = kvsb + (long)bh * 32768;
    float racc[2][4] = {{0.f, 0.f, 0.f, 0.f}, {0.f, 0.f, 0.f, 0.f}};
    #pragma unroll
    for (int i = 0; i < 8; ++i) {
        const int t8 = w * 8 + i;
        const int col = t8 * 16 + c;
        const unsigned short* brow = Bbase + (long)col * 64;
        short8v b0 = *reinterpret_cast<const short8v*>(brow + ko);
        short8v b1 = *reinterpret_cast<const short8v*>(brow + ko + 32);
        f32x4 nacc = {0.f, 0.f, 0.f, 0.f};
        nacc = __builtin_amdgcn_mfma_f32_16x16x32_bf16(a0, b0, nacc, 0, 0, 0);
        nacc = __builtin_amdgcn_mfma_f32_16x16x32_bf16(a1, b1, nacc, 0, 0, 0);
        const int kk = t8 >> 1;       // uniform across wave -> broadcast LDS read
        const int e = t8 & 1;
        #pragma unroll
        for (int j = 0; j < 4; ++j)
            racc[e][j] += nacc[j] * invden[(lane >> 4) * 4 + j][kk];
    }
    #pragma unroll
    for (int e = 0; e < 2; ++e)
        #pragma unroll
        for (int j = 0; j < 4; ++j)
            psum[w][(lane >> 4) * 4 + j][e * 16 + c] = racc[e][j];
    __syncthreads();
    // reduce over waves (= over k groups) + mean + LayerNorm over d
    const int d = t & 31;
    const int r0 = t >> 5;            // 0..7; also handle r0+8
    const float gg = ln_g[d], bb = ln_b[d];
    #pragma unroll
    for (int rr = 0; rr < 2; ++rr) {
        const int row = r0 + rr * 8;
        float s = (psum[0][row][d] + psum[1][row][d]) +
                  (psum[2][row][d] + psum[3][row][d]);
        float zv = s * (1.0f / 16.0f);
        float s1 = zv, s2 = zv * zv;
        #pragma unroll
        for (int off = 1; off < 32; off <<= 1) {
            s1 += __shfl_xor(s1, off);
            s2 += __shfl_xor(s2, off);
        }
        float mu = s1 * (1.0f / 32.0f);
        float var = s2 * (1.0f / 32.0f) - mu * mu;
        float zn = (zv - mu) * rsqrtf(var + 1e-5f) * gg + bb;
        z[(long)(b * L + rt * 16 + row) * 256 + h * 32 + d] = zn;
    }
}

// ---- 7. fused + row L1-normalize ----
__global__ __launch_bounds__(128) void fused_kernel(
    const float* __restrict__ adj, const float* __restrict__ wsm,
    float* __restrict__ fusedn)
{
    __shared__ float part[2];
    const int bi = blockIdx.x;
    const int b = bi / 800;
    const int p = (bi / 100) & 7;
    const int i = bi % 100;
    const int t = threadIdx.x;
    float f = 0.f;
    if (t < 100) {
        #pragma unroll
        for (int pl = 0; pl < 8; ++pl)
            f += adj[((long)(b * 64 + p * 8 + pl)) * NN + i * 100 + t] * wsm[(b * 8 + p) * 8 + pl];
    }
    float a = fabsf(f);
    #pragma unroll
    for (int off = 1; off < 64; off <<= 1) a += __shfl_xor(a, off);
    if ((t & 63) == 0) part[t >> 6] = a;
    __syncthreads();
    float denom = fmaxf(part[0] + part[1], 1e-12f);
    if (t < 100) fusedn[(long)bi * 100 + t] = f / denom;
}

// ---- 8. zb16 = bf16(z + block-diag(fusedn) @ v)  (fused convert) ----
__global__ __launch_bounds__(256) void bias_kernel(
    const float* __restrict__ fusedn, const float* __restrict__ vb,
    const float* __restrict__ z, unsigned short* __restrict__ zb16)
{
    __shared__ float fs[10 * 100];
    const int bi = blockIdx.x;
    const int bp = bi / 10;
    const int b = bp >> 3, p = bp & 7;
    const int i0 = (bi % 10) * 10;
    const int t = threadIdx.x;
    for (int j = t; j < 1000; j += 256)
        fs[j] = fusedn[(long)bp * 10000 + i0 * 100 + j];
    __syncthreads();
    float acc[10];
    #pragma unroll
    for (int r = 0; r < 10; ++r) acc[r] = 0.f;
    for (int j = 0; j < 100; ++j) {
        float vj = vb[(b * 800 + p * 100 + j) * 256 + t];
        #pragma unroll
        for (int r = 0; r < 10; ++r)
            acc[r] += fs[r * 100 + j] * vj;
    }
    for (int r = 0; r < 10; ++r) {
        const long idx = (long)(b * 800 + p * 100 + i0 + r) * 256 + t;
        zb16[idx] = f2b(z[idx] + acc[r]);
    }
}

// ---- 9. out via MFMA: [6400x256] @ [256x256] + bias ----
__global__ __launch_bounds__(256) void out_mfma_kernel(
    const unsigned short* __restrict__ zb, const unsigned short* __restrict__ wob,
    const float* __restrict__ bo, float* __restrict__ out)
{
    const int task = blockIdx.x * 4 + (threadIdx.x >> 6);  // 6400 tasks
    const int nt = task & 15;
    const int mt = task >> 4;            // 0..399
    const int lane = threadIdx.x & 63;
    const int row = lane & 15;
    const int ko = (lane >> 4) * 8;
    const unsigned short* pa = zb + (long)(mt * 16 + row) * 256 + ko;
    const unsigned short* pb = wob + (long)(nt * 16 + row) * 256 + ko;
    f32x4 acc = {0.f, 0.f, 0.f, 0.f};
    #pragma unroll
    for (int s = 0; s < 8; ++s) {
        short8v a = *reinterpret_cast<const short8v*>(pa + s * 32);
        short8v b = *reinterpret_cast<const short8v*>(pb + s * 32);
        acc = __builtin_amdgcn_mfma_f32_16x16x32_bf16(a, b, acc, 0, 0, 0);
    }
    const int col = nt * 16 + (lane & 15);
    const float bias = bo[col];
    const int rbase = mt * 16 + (lane >> 4) * 4;
    #pragma unroll
    for (int j = 0; j < 4; ++j)
        out[(long)(rbase + j) * 256 + col] = acc[j] + bias;
}

extern "C" void kernel_launch(void* const* d_in, const int* in_sizes, int n_in,
                              void* d_out, int out_size, void* d_ws, size_t ws_size,
                              hipStream_t stream) {
    const float* x     = (const float*)d_in[0];
    const float* adj   = (const float*)d_in[1];
    const float* Wq_w  = (const float*)d_in[2];
    const float* Wq_b  = (const float*)d_in[3];
    const float* Wk_w  = (const float*)d_in[4];
    const float* Wk_b  = (const float*)d_in[5];
    const float* Wv_w  = (const float*)d_in[6];
    const float* Wv_b  = (const float*)d_in[7];
    const float* Wo_w  = (const float*)d_in[8];
    const float* Wo_b  = (const float*)d_in[9];
    const float* ln_g  = (const float*)d_in[10];
    const float* ln_b  = (const float*)d_in[11];
    const float* fc_w  = (const float*)d_in[12];
    const float* fc_b  = (const float*)d_in[13];
    const float* out_w = (const float*)d_in[14];
    const float* out_b = (const float*)d_in[15];
    const float* proj  = (const float*)d_in[16];
    const float* gum   = (const float*)d_in[17];
    float* out = (float*)d_out;

    // ---- workspace layout (float units) — overlay tenants, disjoint lifetimes ----
    float* ws = (float*)d_ws;
    const size_t wsfl = ws_size / sizeof(float);
    constexpr size_t AFTER_NEED = 8540288;
    const int nsplit = (wsfl >= (size_t)6 * 2162688 + AFTER_NEED) ? 6 : 3;
    const size_t OVL = (size_t)nsplit * 2162688;

    float* ovl = ws;
    unsigned short* adjb = (unsigned short*)ovl;              // 512*10240 bf16
    unsigned short* fcwb = (unsigned short*)(ovl + 2621440);  // 128*10240 bf16
    float* h1part  = ovl + 3276800;       // 524,288
    float* qbuf    = ovl;                 // 1,638,400
    float* kbuf    = ovl + 1638400;       // 1,638,400
    unsigned short* xb    = (unsigned short*)(ovl + 3276800); // 1,638,400 bf16
    unsigned short* wqkvb = (unsigned short*)(ovl + 4096000); // 196,608 bf16
    float* kvspart = ovl;                 // nsplit * 2,097,152 (transposed [k][d][m])
    float* ksumpart= ovl + (size_t)nsplit * 2097152;  // nsplit * 65,536
    float* zbuf    = ovl;                 // 1,638,400
    float* fusedn  = ovl + 1638400;       // 640,000

    float* after   = ws + OVL;
    float* vbuf    = after;                                   // 1,638,400
    unsigned short* qpb = (unsigned short*)(vbuf + 1638400);  // 3,276,800 bf16 (1,638,400 fl)
    float* kp      = vbuf + 1638400 + 1638400;                // 3,276,800 (raw dd for keys)
    float* diagk   = kp + 3276800;                            // 51,200
    unsigned short* kvsb  = (unsigned short*)(diagk + 51200); // 2,097,152 bf16 (1,048,576 fl)
    unsigned short* ksumb = (unsigned short*)(diagk + 51200 + 1048576); // 65,536 bf16 (32,768 fl)
    float* wsm     = diagk + 51200 + 1048576 + 32768;         // 512
    float* partmax = wsm + 512;                               // 1,600
    float* kmax    = partmax + 1600;                          // 64
    unsigned short* wob  = (unsigned short*)(kmax + 64);      // 65,536 bf16 (32,768 fl)
    unsigned short* zb16 = (unsigned short*)(kmax + 64 + 32768); // 1,638,400 bf16 (819,200 fl)

    // adj path first so t1 tenants die before qkv
    convert_kernel<<<dim3(40, 640), 256, 0, stream>>>(adj, fc_w, adjb, fcwb);
    adjfc_mfma_kernel<<<512, 256, 0, stream>>>(adjb, fcwb, h1part);
    wsm_kernel<<<64, 128, 0, stream>>>(h1part, fc_b, out_w, out_b, wsm);

    convert_xw_kernel<<<7424, 256, 0, stream>>>(x, Wq_w, Wk_w, Wv_w, Wo_w,
                                                xb, wqkvb, wob);
    qkv_mfma_kernel<<<4800, 256, 0, stream>>>(xb, wqkvb, Wq_b, Wk_b, Wv_b,
                                              qbuf, kbuf, vbuf);
    phiqk_kernel<<<3200, 256, 0, stream>>>(qbuf, kbuf, proj, qpb, kp, diagk, partmax);
    kmax_kernel<<<64, 64, 0, stream>>>(partmax, kmax);
    kvs_kernel<<<64 * nsplit * 4, 256, 0, stream>>>(kp, diagk, kmax, vbuf, gum,
                                                    kvspart, ksumpart, nsplit);
    kvsreduce_kernel<<<2112, 256, 0, stream>>>(kvspart, ksumpart, kvsb, ksumb, nsplit);
    z_mfma_kernel<<<3200, 256, 0, stream>>>(qpb, kvsb, ksumb, ln_g, ln_b, zbuf);
    fused_kernel<<<6400, 128, 0, stream>>>(adj, wsm, fusedn);
    bias_kernel<<<640, 256, 0, stream>>>(fusedn, vbuf, zbuf, zb16);
    out_mfma_kernel<<<1600, 256, 0, stream>>>(zb16, wob, Wo_b, out);
}